// Round 12
// baseline (502.459 us; speedup 1.0000x reference)
//
#include <hip/hip_runtime.h>

typedef __attribute__((ext_vector_type(8))) short short8;
typedef __attribute__((ext_vector_type(4))) float f32x4;

#define MAXN   20480  // LDS histogram capacity (n = 20000)
#define NSLICE 8      // feature slices (32 floats each) -> XCD pinning
#define NPB    40     // nodes per pull block chunk (10 per wave)

// ---------------------------------------------------------------- bf16 split helpers
__device__ inline unsigned short f2bf(float v) {
    unsigned u = __float_as_uint(v);
    u += 0x7FFFu + ((u >> 16) & 1u);   // RNE
    return (unsigned short)(u >> 16);
}
__device__ inline float bf2f(unsigned short h) {
    return __uint_as_float((unsigned)h << 16);
}

// ---------------------------------------------------------------- W prep (+ fused bias sums)
// Bpk layout: [ntile(16)][kstep(16)][plane(2)][lane(64)][8] shorts.
__global__ void wprep_kernel(const float* __restrict__ W1s, const float* __restrict__ W1u,
                             const float* __restrict__ W2s, const float* __restrict__ W2u,
                             const float* __restrict__ b1s, const float* __restrict__ b1u,
                             const float* __restrict__ b2s, const float* __restrict__ b2u,
                             unsigned short* __restrict__ Bpk1, unsigned short* __restrict__ Bpk2,
                             float* __restrict__ bsum1, float* __restrict__ bsum2) {
    int k = blockIdx.x;        // 0..511
    int nn = threadIdx.x;      // 0..255
    int layer = blockIdx.y;
    if (k == 0) {
        if (layer) bsum2[nn] = b2s[nn] + b2u[nn];
        else       bsum1[nn] = b1s[nn] + b1u[nn];
    }
    const float* Ws = layer ? W2s : W1s;
    const float* Wu = layer ? W2u : W1u;
    float w = (k < 256) ? Ws[k * 256 + nn] : Wu[(k - 256) * 256 + nn];
    unsigned short hi = f2bf(w);
    unsigned short lo = f2bf(w - bf2f(hi));
    unsigned short* B = layer ? Bpk2 : Bpk1;
    size_t frag = ((size_t)(nn >> 4) * 16 + (k >> 5)) * 2;           // *2 planes
    size_t addr = frag * 512 + ((nn & 15) + ((k >> 3) & 3) * 16) * 8 + (k & 7);
    B[addr] = hi;          // plane 0
    B[addr + 512] = lo;    // plane 1
}

// ---------------------------------------------------------------- phase H: per-block packed histograms
__global__ __launch_bounds__(256) void hist_kernel(
    const int* __restrict__ sS, const int* __restrict__ dS,
    const int* __restrict__ sU, const int* __restrict__ dU,
    int Es, int Eu, int n, int nblk, unsigned int* __restrict__ histG) {
    __shared__ unsigned int h[MAXN];
    const int rel = blockIdx.y;
    const int* src = rel ? sU : sS;
    const int* dst = rel ? dU : dS;
    int E = rel ? Eu : Es;
    int b = blockIdx.x;
    int chunk = (E + nblk - 1) / nblk;
    int beg = b * chunk;
    int end = min(E, beg + chunk);
    for (int i = threadIdx.x; i < n; i += 256) h[i] = 0u;
    __syncthreads();
    for (int i = beg + threadIdx.x; i < end; i += 256) {
        atomicAdd(&h[src[i]], 1u);
        atomicAdd(&h[dst[i]], 0x10000u);
    }
    __syncthreads();
    unsigned int* out = histG + ((size_t)rel * nblk + b) * n;
    for (int i = threadIdx.x; i < n; i += 256) out[i] = h[i];
}

// ---------------------------------------------------------------- phase B1: totals -> scales + deg_in + chunk sums
// Unrolled x8 (8 strided loads in flight). Fused: block-level deg_in partial
// sum for the row_ptr scan (replaces the old scan_part kernel).
__global__ __launch_bounds__(256) void totals_kernel(
    const unsigned int* __restrict__ histG, int n, int nblk,
    float* __restrict__ sOutS, float* __restrict__ sInS,
    float* __restrict__ sOutU, float* __restrict__ sInU,
    int* __restrict__ degInS, int* __restrict__ degInU,
    int* __restrict__ chunkSum /* [2][NCH] */) {
    const int rel = blockIdx.y;
    int i = blockIdx.x * 256 + threadIdx.x;
    unsigned int lo = 0, hi = 0;
    if (i < n) {
        const unsigned int* hg = histG + (size_t)rel * nblk * n + i;
        int b = 0;
        for (; b + 8 <= nblk; b += 8) {
            unsigned v0 = hg[(size_t)(b + 0) * n];
            unsigned v1 = hg[(size_t)(b + 1) * n];
            unsigned v2 = hg[(size_t)(b + 2) * n];
            unsigned v3 = hg[(size_t)(b + 3) * n];
            unsigned v4 = hg[(size_t)(b + 4) * n];
            unsigned v5 = hg[(size_t)(b + 5) * n];
            unsigned v6 = hg[(size_t)(b + 6) * n];
            unsigned v7 = hg[(size_t)(b + 7) * n];
            lo += (v0 & 0xFFFFu) + (v1 & 0xFFFFu) + (v2 & 0xFFFFu) + (v3 & 0xFFFFu)
                + (v4 & 0xFFFFu) + (v5 & 0xFFFFu) + (v6 & 0xFFFFu) + (v7 & 0xFFFFu);
            hi += (v0 >> 16) + (v1 >> 16) + (v2 >> 16) + (v3 >> 16)
                + (v4 >> 16) + (v5 >> 16) + (v6 >> 16) + (v7 >> 16);
        }
        for (; b < nblk; ++b) {
            unsigned v = hg[(size_t)b * n];
            lo += v & 0xFFFFu;
            hi += v >> 16;
        }
        float so = rsqrtf((float)(lo > 1u ? lo : 1u));
        float si = rsqrtf((float)(hi > 1u ? hi : 1u));
        if (rel) { sOutU[i] = so; sInU[i] = si; degInU[i] = (int)hi; }
        else     { sOutS[i] = so; sInS[i] = si; degInS[i] = (int)hi; }
    }
    __shared__ int sm[256];
    int t = threadIdx.x;
    sm[t] = (i < n) ? (int)hi : 0;
    __syncthreads();
    for (int off = 128; off > 0; off >>= 1) {
        if (t < off) sm[t] += sm[t + off];
        __syncthreads();
    }
    if (t == 0) chunkSum[rel * gridDim.x + blockIdx.x] = sm[0];
}

// ---------------------------------------------------------------- scan mid: exclusive scan of chunk sums (in-place)
__global__ void scan_mid_kernel(int* __restrict__ chunkSum, int NCH,
                                int* __restrict__ rpS, int* __restrict__ rpU, int n) {
    int t = threadIdx.x;
    if (t >= 2) return;
    int* cs = chunkSum + t * NCH;
    int run = 0;
    for (int i = 0; i < NCH; ++i) {
        int v = cs[i];
        cs[i] = run;
        run += v;
    }
    int* rp = t ? rpU : rpS;
    rp[n] = run;
}

// ---------------------------------------------------------------- scan final: rp[i] = chunkPfx + intra-chunk excl
__global__ __launch_bounds__(256) void scan_final_kernel(
    const int* __restrict__ degInS, const int* __restrict__ degInU,
    const int* __restrict__ chunkPfx, int n,
    int* __restrict__ rpS, int* __restrict__ rpU) {
    const int rel = blockIdx.y;
    const int* deg = rel ? degInU : degInS;
    int* rp = rel ? rpU : rpS;
    int t = threadIdx.x;
    int i = blockIdx.x * 256 + t;
    int v = (i < n) ? deg[i] : 0;
    __shared__ int sm[256];
    sm[t] = v;
    __syncthreads();
    #pragma unroll
    for (int off = 1; off < 256; off <<= 1) {
        int y = (t >= off) ? sm[t - off] : 0;
        __syncthreads();
        sm[t] += y;
        __syncthreads();
    }
    if (i < n) rp[i] = chunkPfx[rel * gridDim.x + blockIdx.x] + sm[t] - v;
}

// ---------------------------------------------------------------- phase B2: per-block scatter offsets
__global__ void offsets_kernel(const unsigned int* __restrict__ histG,
                               const int* __restrict__ rpS, const int* __restrict__ rpU,
                               int n, int nblk, int* __restrict__ offsG) {
    const int rel = blockIdx.y;
    int i = blockIdx.x * 256 + threadIdx.x;
    if (i >= n) return;
    const unsigned int* hg = histG + (size_t)rel * nblk * n + i;
    int* og = offsG + (size_t)rel * nblk * n + i;
    int run = (rel ? rpU : rpS)[i];
    int b = 0;
    for (; b + 8 <= nblk; b += 8) {
        unsigned v0 = hg[(size_t)(b + 0) * n];
        unsigned v1 = hg[(size_t)(b + 1) * n];
        unsigned v2 = hg[(size_t)(b + 2) * n];
        unsigned v3 = hg[(size_t)(b + 3) * n];
        unsigned v4 = hg[(size_t)(b + 4) * n];
        unsigned v5 = hg[(size_t)(b + 5) * n];
        unsigned v6 = hg[(size_t)(b + 6) * n];
        unsigned v7 = hg[(size_t)(b + 7) * n];
        og[(size_t)(b + 0) * n] = run; run += (int)(v0 >> 16);
        og[(size_t)(b + 1) * n] = run; run += (int)(v1 >> 16);
        og[(size_t)(b + 2) * n] = run; run += (int)(v2 >> 16);
        og[(size_t)(b + 3) * n] = run; run += (int)(v3 >> 16);
        og[(size_t)(b + 4) * n] = run; run += (int)(v4 >> 16);
        og[(size_t)(b + 5) * n] = run; run += (int)(v5 >> 16);
        og[(size_t)(b + 6) * n] = run; run += (int)(v6 >> 16);
        og[(size_t)(b + 7) * n] = run; run += (int)(v7 >> 16);
    }
    for (; b < nblk; ++b) {
        unsigned v = hg[(size_t)b * n];
        og[(size_t)b * n] = run;
        run += (int)(v >> 16);
    }
}

// ---------------------------------------------------------------- phase C: CSR scatter, packed (u, w) + tail pad
__global__ __launch_bounds__(256) void csr_scatter_kernel(
    const int* __restrict__ sS, const int* __restrict__ dS,
    const int* __restrict__ sU, const int* __restrict__ dU,
    int Es, int Eu, int n, int nblk, const int* __restrict__ offsG,
    const float* __restrict__ sOutS, const float* __restrict__ sOutU,
    int2* __restrict__ csrPS, int2* __restrict__ csrPU) {
    __shared__ int off[MAXN];
    const int rel = blockIdx.y;
    const int* src = rel ? sU : sS;
    const int* dst = rel ? dU : dS;
    const float* so = rel ? sOutU : sOutS;
    int2* csrP = rel ? csrPU : csrPS;
    int E = rel ? Eu : Es;
    int b = blockIdx.x;
    // zero the 64-entry tail pad (enables maskless over-read in pull)
    if (b == 0 && threadIdx.x < 64) csrP[E + threadIdx.x] = make_int2(0, 0);
    int chunk = (E + nblk - 1) / nblk;  // MUST match hist_kernel
    int beg = b * chunk;
    int end = min(E, beg + chunk);
    const int* og = offsG + ((size_t)rel * nblk + b) * n;
    for (int i = threadIdx.x; i < n; i += 256) off[i] = og[i];
    __syncthreads();
    for (int i = beg + threadIdx.x; i < end; i += 256) {
        int s = src[i];
        int pos = atomicAdd(&off[dst[i]], 1);
        csrP[pos] = make_int2(s, __float_as_int(so[s]));
    }
}

// ---------------------------------------------------------------- sliced pull aggregation, direct edge-load
// block = (chunk, rel, slice); slice = blockIdx.x & 7 pins slice -> XCD (2.56 MB/XCD L2).
// Wave: one node at a time; 8 subgroups x 8 lanes. Each subgroup's 8 lanes load
// the SAME 8B edge record directly from csrP (the wave's 64 addresses span ONE
// 64B line -> 1 transaction, HW broadcast) — replaces the 2-bpermute/edge
// broadcast AND the 64-edge register staging phase. Full 8-edge steps are
// maskless (jfull = deg>>3); one masked tail step; csrP has a 64-entry zero pad
// so over-reads are safe (w=0 kills any neighbor-node contribution).
__global__ __launch_bounds__(256) void pull_slice_kernel(
    const float4* __restrict__ xin,      // [n][64] float4
    const int2* __restrict__ csrPS, const int2* __restrict__ csrPU,
    const int* __restrict__ rpS, const int* __restrict__ rpU,
    const float* __restrict__ sinS, const float* __restrict__ sinU,
    unsigned short* __restrict__ aggPk, int n) {
    int bid = blockIdx.x;
    int slice = bid & (NSLICE - 1);
    int rest = bid >> 3;
    int rel = rest & 1;
    int chunk = rest >> 1;
    const int2* csrP = rel ? csrPU : csrPS;
    const int* rp = rel ? rpU : rpS;
    const float* sinv = rel ? sinU : sinS;

    int wave = threadIdx.x >> 6;
    int lane = threadIdx.x & 63;
    int sub = lane >> 3;          // 0..7 edge slot
    int sl = lane & 7;            // float4 index within slice
    int fbase = slice * 8 + sl;   // float4 index within a 64-float4 row
    int kstepg = rel * 8 + slice;

    int start = chunk * NPB;
    int lim = min(n, start + NPB);
    for (int node = start + wave; node < lim; node += 4) {
        int beg = rp[node], end = rp[node + 1];
        int deg = end - beg;
        float ax = 0.f, ay = 0.f, az = 0.f, aw = 0.f;
        const int2* ep = csrP + beg + sub;
        int jfull = deg >> 3;
        int j = 0;
        for (; j + 4 <= jfull; j += 4) {
            int2 e0 = ep[(j + 0) * 8];
            int2 e1 = ep[(j + 1) * 8];
            int2 e2 = ep[(j + 2) * 8];
            int2 e3 = ep[(j + 3) * 8];
            float4 a0 = xin[(size_t)e0.x * 64 + fbase];
            float4 a1 = xin[(size_t)e1.x * 64 + fbase];
            float4 a2 = xin[(size_t)e2.x * 64 + fbase];
            float4 a3 = xin[(size_t)e3.x * 64 + fbase];
            float w0 = __int_as_float(e0.y), w1 = __int_as_float(e1.y);
            float w2 = __int_as_float(e2.y), w3 = __int_as_float(e3.y);
            ax += w0 * a0.x + w1 * a1.x + w2 * a2.x + w3 * a3.x;
            ay += w0 * a0.y + w1 * a1.y + w2 * a2.y + w3 * a3.y;
            az += w0 * a0.z + w1 * a1.z + w2 * a2.z + w3 * a3.z;
            aw += w0 * a0.w + w1 * a1.w + w2 * a2.w + w3 * a3.w;
        }
        for (; j < jfull; ++j) {
            int2 e = ep[j * 8];
            float4 a = xin[(size_t)e.x * 64 + fbase];
            float w = __int_as_float(e.y);
            ax += w * a.x; ay += w * a.y; az += w * a.z; aw += w * a.w;
        }
        if (deg & 7) {
            int idx = jfull * 8 + sub;
            int2 e = ep[jfull * 8];              // safe: 64-entry zero pad
            float w = (idx < deg) ? __int_as_float(e.y) : 0.f;
            float4 a = xin[(size_t)e.x * 64 + fbase];  // e.x always in [0,n)
            ax += w * a.x; ay += w * a.y; az += w * a.z; aw += w * a.w;
        }
        // reduce across the 8 subgroups (lane bits 3,4,5)
        ax += __shfl_xor(ax, 8);  ax += __shfl_xor(ax, 16); ax += __shfl_xor(ax, 32);
        ay += __shfl_xor(ay, 8);  ay += __shfl_xor(ay, 16); ay += __shfl_xor(ay, 32);
        az += __shfl_xor(az, 8);  az += __shfl_xor(az, 16); az += __shfl_xor(az, 32);
        aw += __shfl_xor(aw, 8);  aw += __shfl_xor(aw, 16); aw += __shfl_xor(aw, 32);
        if (sub == 0) {
            float si = sinv[node];
            float vx = si * ax, vy = si * ay, vz = si * az, vw = si * aw;
            ushort4 hi4 = make_ushort4(f2bf(vx), f2bf(vy), f2bf(vz), f2bf(vw));
            ushort4 lo4 = make_ushort4(f2bf(vx - bf2f(hi4.x)), f2bf(vy - bf2f(hi4.y)),
                                       f2bf(vz - bf2f(hi4.z)), f2bf(vw - bf2f(hi4.w)));
            // fragment-packed store: kstep = rel*8+slice
            size_t frag = ((size_t)(node >> 4) * 16 + kstepg) * 2;
            size_t addr = frag * 512 + ((node & 15) + (sl >> 1) * 16) * 8 + (sl & 1) * 4;
            *(ushort4*)&aggPk[addr] = hi4;
            *(ushort4*)&aggPk[addr + 512] = lo4;
        }
    }
}

// ---------------------------------------------------------------- split-bf16 MFMA GEMM, LDS double-buffered
// C[M x 256] = (Ahi+Alo)[M x 512] @ W (+bias)(+relu), hi*hi + lo*hi + hi*lo.
// BM=80 (5 mtiles) x full 256 cols; 512 threads / 8 waves, wave = 2 ntiles.
// Double-buffer: global loads for ks+1 fly during MFMA of ks; ONE barrier/k-step.
template <int RELU>
__global__ __launch_bounds__(512) void gemm_mfma_kernel(
    const short8* __restrict__ Apk, const short8* __restrict__ Bpk,
    const float* __restrict__ bias, float* __restrict__ C, int M) {
    __shared__ short8 lds[2][42][64];   // 2 x 42 frags x 64 lanes x 16B = 84KB
    int tid = threadIdx.x;
    int lane = tid & 63;
    int wv = tid >> 6;     // 0..7
    int mt0 = blockIdx.x * 5;
    int m0 = blockIdx.x * 80;
    if (m0 >= M) return;
    int nt0 = wv * 2;
    int col0 = wv * 32;
    int frow = lane & 15;

    int sf[6], sln[6];
    bool sv[6];
    #pragma unroll
    for (int r = 0; r < 6; ++r) {
        int s = r * 512 + tid;
        sv[r] = s < 2688;
        sf[r] = s >> 6;
        sln[r] = s & 63;
    }
    auto gaddr = [&](int f, int l, int ks) -> size_t {
        if (f < 10) {
            return ((size_t)(mt0 + (f >> 1)) * 16 + ks) * 128 + (f & 1) * 64 + l;
        } else {
            int q = f - 10;
            return ((size_t)(q >> 1) * 16 + ks) * 128 + (q & 1) * 64 + l;
        }
    };

    f32x4 acc[5][2];
    #pragma unroll
    for (int fr = 0; fr < 5; ++fr)
        #pragma unroll
        for (int fc = 0; fc < 2; ++fc)
            acc[fr][fc] = (f32x4){0.f, 0.f, 0.f, 0.f};

    short8 stg[6];
    #pragma unroll
    for (int r = 0; r < 6; ++r)
        if (sv[r]) stg[r] = (sf[r] < 10 ? Apk : Bpk)[gaddr(sf[r], sln[r], 0)];
    #pragma unroll
    for (int r = 0; r < 6; ++r)
        if (sv[r]) lds[0][sf[r]][sln[r]] = stg[r];
    __syncthreads();

    int cur = 0;
    for (int ks = 0; ks < 16; ++ks) {
        if (ks + 1 < 16) {
            #pragma unroll
            for (int r = 0; r < 6; ++r)
                if (sv[r]) stg[r] = (sf[r] < 10 ? Apk : Bpk)[gaddr(sf[r], sln[r], ks + 1)];
        }
        short8 bh[2], bl[2];
        #pragma unroll
        for (int fc = 0; fc < 2; ++fc) {
            bh[fc] = lds[cur][10 + (nt0 + fc) * 2 + 0][lane];
            bl[fc] = lds[cur][10 + (nt0 + fc) * 2 + 1][lane];
        }
        #pragma unroll
        for (int fr = 0; fr < 5; ++fr) {
            short8 ah = lds[cur][fr * 2 + 0][lane];
            short8 al = lds[cur][fr * 2 + 1][lane];
            #pragma unroll
            for (int fc = 0; fc < 2; ++fc) {
                acc[fr][fc] = __builtin_amdgcn_mfma_f32_16x16x32_bf16(ah, bh[fc], acc[fr][fc], 0, 0, 0);
                acc[fr][fc] = __builtin_amdgcn_mfma_f32_16x16x32_bf16(al, bh[fc], acc[fr][fc], 0, 0, 0);
                acc[fr][fc] = __builtin_amdgcn_mfma_f32_16x16x32_bf16(ah, bl[fc], acc[fr][fc], 0, 0, 0);
            }
        }
        if (ks + 1 < 16) {
            #pragma unroll
            for (int r = 0; r < 6; ++r)
                if (sv[r]) lds[cur ^ 1][sf[r]][sln[r]] = stg[r];
            __syncthreads();
            cur ^= 1;
        }
    }

    #pragma unroll
    for (int fr = 0; fr < 5; ++fr)
        #pragma unroll
        for (int fc = 0; fc < 2; ++fc) {
            int c = col0 + fc * 16 + frow;
            float bc = bias[c];
            int rb = m0 + fr * 16 + (lane >> 4) * 4;
            #pragma unroll
            for (int j = 0; j < 4; ++j) {
                int r = rb + j;
                if (r < M) {
                    float v = acc[fr][fc][j] + bc;
                    if (RELU) v = fmaxf(v, 0.f);
                    C[(size_t)r * 256 + c] = v;
                }
            }
        }
}

// ---------------------------------------------------------------- launch
extern "C" void kernel_launch(void* const* d_in, const int* in_sizes, int n_in,
                              void* d_out, int out_size, void* d_ws, size_t ws_size,
                              hipStream_t stream) {
    const float* x   = (const float*)d_in[0];
    const int* sS    = (const int*)d_in[1];
    const int* dS    = (const int*)d_in[2];
    const int* sU    = (const int*)d_in[3];
    const int* dU    = (const int*)d_in[4];
    const float* W1s = (const float*)d_in[5];
    const float* b1s = (const float*)d_in[6];
    const float* W1u = (const float*)d_in[7];
    const float* b1u = (const float*)d_in[8];
    const float* W2s = (const float*)d_in[9];
    const float* b2s = (const float*)d_in[10];
    const float* W2u = (const float*)d_in[11];
    const float* b2u = (const float*)d_in[12];
    float* out = (float*)d_out;

    const int n  = in_sizes[0] / 256;
    const int Es = in_sizes[1];
    const int Eu = in_sizes[3];
    const int NCH = (n + 255) / 256;
    const int gemmGrid = (n + 79) / 80;
    const size_t AGG_BYTES = (size_t)((n + 15) / 16 + 16) * 16 * 2 * 512 * 2;
    const size_t BPK_BYTES = (size_t)16 * 16 * 2 * 512 * 2;

    auto plan = [&](int nb) -> size_t {
        size_t t = 0;
        auto add = [&](size_t b) { t = (t + 255) & ~(size_t)255; t += b; };
        add((size_t)2 * nb * n * 4);            // histG
        add((size_t)2 * nb * n * 4);            // offsG
        add((size_t)(n + 1) * 4); add((size_t)(n + 1) * 4);
        add((size_t)n * 4); add((size_t)n * 4); add((size_t)n * 4); add((size_t)n * 4);
        add((size_t)n * 4); add((size_t)n * 4); // degIn
        add(256 * 4); add(256 * 4);
        add((size_t)2 * NCH * 4);               // chunkSum
        add((size_t)(Es + 64) * 8); add((size_t)(Eu + 64) * 8);
        add(2 * BPK_BYTES);
        add(AGG_BYTES);
        add((size_t)n * 256 * 4);               // h
        return t;
    };
    const int nblk = (plan(64) <= ws_size) ? 64 : 32;

    char* ws = (char*)d_ws;
    size_t off = 0;
    auto alloc = [&](size_t bytes) -> void* {
        off = (off + 255) & ~(size_t)255;
        void* p = ws + off;
        off += bytes;
        return p;
    };

    unsigned int* histG = (unsigned int*)alloc((size_t)2 * nblk * n * 4);
    int* offsG   = (int*)alloc((size_t)2 * nblk * n * 4);
    int* rpS     = (int*)alloc((size_t)(n + 1) * 4);
    int* rpU     = (int*)alloc((size_t)(n + 1) * 4);
    float* sOutS = (float*)alloc((size_t)n * 4);
    float* sInS  = (float*)alloc((size_t)n * 4);
    float* sOutU = (float*)alloc((size_t)n * 4);
    float* sInU  = (float*)alloc((size_t)n * 4);
    int* degInS  = (int*)alloc((size_t)n * 4);
    int* degInU  = (int*)alloc((size_t)n * 4);
    float* bsum1 = (float*)alloc(256 * 4);
    float* bsum2 = (float*)alloc(256 * 4);
    int* chunkSum = (int*)alloc((size_t)2 * NCH * 4);
    int2* csrPS  = (int2*)alloc((size_t)(Es + 64) * 8);
    int2* csrPU  = (int2*)alloc((size_t)(Eu + 64) * 8);
    unsigned short* Bpk1 = (unsigned short*)alloc(2 * BPK_BYTES);
    unsigned short* Bpk2 = Bpk1 + BPK_BYTES / 2;
    unsigned short* aggPk = (unsigned short*)alloc(AGG_BYTES);
    float* h     = (float*)alloc((size_t)n * 256 * 4);

    // ---- preprocessing (no global atomics)
    wprep_kernel<<<dim3(512, 2), 256, 0, stream>>>(W1s, W1u, W2s, W2u,
                                                   b1s, b1u, b2s, b2u,
                                                   Bpk1, Bpk2, bsum1, bsum2);
    dim3 hg(nblk, 2);
    hist_kernel<<<hg, 256, 0, stream>>>(sS, dS, sU, dU, Es, Eu, n, nblk, histG);
    dim3 tg(NCH, 2);
    totals_kernel<<<tg, 256, 0, stream>>>(histG, n, nblk, sOutS, sInS, sOutU, sInU,
                                          degInS, degInU, chunkSum);
    scan_mid_kernel<<<1, 64, 0, stream>>>(chunkSum, NCH, rpS, rpU, n);
    scan_final_kernel<<<tg, 256, 0, stream>>>(degInS, degInU, chunkSum, n, rpS, rpU);
    offsets_kernel<<<tg, 256, 0, stream>>>(histG, rpS, rpU, n, nblk, offsG);
    csr_scatter_kernel<<<hg, 256, 0, stream>>>(sS, dS, sU, dU, Es, Eu, n, nblk, offsG,
                                               sOutS, sOutU, csrPS, csrPU);

    // ---- layers
    int chunks = (n + NPB - 1) / NPB;
    int pullGrid = NSLICE * 2 * chunks;
    const float4* x4 = (const float4*)x;
    const float4* h4 = (const float4*)h;
    const short8* A8 = (const short8*)aggPk;
    const short8* B81 = (const short8*)Bpk1;
    const short8* B82 = (const short8*)Bpk2;

    pull_slice_kernel<<<pullGrid, 256, 0, stream>>>(x4, csrPS, csrPU, rpS, rpU,
                                                    sInS, sInU, aggPk, n);
    gemm_mfma_kernel<1><<<gemmGrid, 512, 0, stream>>>(A8, B81, bsum1, h, n);
    pull_slice_kernel<<<pullGrid, 256, 0, stream>>>(h4, csrPS, csrPU, rpS, rpU,
                                                    sInS, sInU, aggPk, n);
    gemm_mfma_kernel<0><<<gemmGrid, 512, 0, stream>>>(A8, B82, bsum2, out, n);
}